// Round 4
// baseline (114.241 us; speedup 1.0000x reference)
//
#include <hip/hip_runtime.h>
#include <cstdint>
#include <cstddef>

#define CIN   64
#define CH_   64
#define CW_   64
#define COUT  128

typedef short  s16x8  __attribute__((ext_vector_type(8)));
typedef float  f32x16 __attribute__((ext_vector_type(16)));

__device__ __forceinline__ unsigned short f32_to_bf16(float f) {
    unsigned int u = __builtin_bit_cast(unsigned int, f);
    u = u + 0x7FFFu + ((u >> 16) & 1u);          // RNE
    return (unsigned short)(u >> 16);
}

// ---- pre-kernel: f32 (C*9, 128) -> bf16 [tap][chunk][co][8ch], fully coalesced reads
__global__ __launch_bounds__(256) void wconv_prep(const float* __restrict__ wgt,
                                                  unsigned short* __restrict__ wdst) {
    int tid = blockIdx.x * 256 + threadIdx.x;
    if (tid >= 576 * 128) return;
    int row = tid >> 7;            // c*9 + tap
    int co  = tid & 127;
    int c   = row / 9;
    int tap = row - c * 9;
    float f = wgt[tid];            // coalesced
    wdst[((tap * 8 + (c >> 3)) * 128 + co) * 8 + (c & 7)] = f32_to_bf16(f);
}

// ---- main: implicit GEMM, 128(spatial=2h x 64w) x 128(co) per block
// LDS x geometry: [r:4][ck:8][t:66] with row stride 67*16 B -> conflict-free reads AND writes
#define XROW 1072   // 67 * 16 bytes
__global__ __launch_bounds__(256, 4) void conv_mfma(
    const float* __restrict__ x,            // (N,64,64,64) f32
    const float* __restrict__ bias,         // (128)
    const unsigned short* __restrict__ wbf, // bf16 [tap][chunk][co][8], in ws (L2-resident)
    float* __restrict__ out)                // (N,128,64,64) f32
{
    __shared__ __align__(16) unsigned char lds_x[32 * XROW];   // 34304 B

    const int tid  = threadIdx.x;
    const int lane = tid & 63;
    const int wid  = tid >> 6;
    const int hi   = lane >> 5;
    const int l31  = lane & 31;
    const int wm   = wid >> 1;
    const int wn   = wid & 1;

    // XCD-bijective swizzle: 1024 blocks = 8 * 128
    const int bid = blockIdx.x;
    const int swz = (bid & 7) * 128 + (bid >> 3);
    const int n   = swz >> 5;
    const int hb  = swz & 31;
    const int h0  = hb * 2;

    const float* xn = x + (size_t)n * CIN * CH_ * CW_;

    // ---- stage x tile: rows h0-1..h0+2 (r=0..3), cols -1..64 (t=0..65), 64 ch bf16
    #pragma unroll
    for (int it = 0; it < 2; ++it) {
        const int idx = tid + it * 256;         // 512 items
        const int g  = idx & 15;                // w-group of 4
        const int ck = (idx >> 4) & 7;          // channel chunk
        const int r  = idx >> 7;                // tile row 0..3
        const int grow = h0 - 1 + r;
        s16x8 pk[4] = {};
        if (grow >= 0 && grow < CH_) {
            #pragma unroll
            for (int e = 0; e < 8; ++e) {
                const float4 v = *(const float4*)(xn + ((size_t)(ck * 8 + e) * CH_ + grow) * CW_ + 4 * g);
                pk[0][e] = (short)f32_to_bf16(v.x);
                pk[1][e] = (short)f32_to_bf16(v.y);
                pk[2][e] = (short)f32_to_bf16(v.z);
                pk[3][e] = (short)f32_to_bf16(v.w);
            }
        }
        unsigned char* rowp = lds_x + (r * 8 + ck) * XROW;
        #pragma unroll
        for (int q = 0; q < 4; ++q)
            *(s16x8*)(rowp + (4 * g + 1 + q) * 16) = pk[q];
    }
    if (tid < 64) {   // zero pads t=0 (gcol=-1) and t=65 (gcol=64)
        const int t  = (tid & 1) ? 65 : 0;
        const int ck = (tid >> 1) & 7;
        const int r  = tid >> 4;
        s16x8 z = {};
        *(s16x8*)(lds_x + (r * 8 + ck) * XROW + t * 16) = z;
    }
    __syncthreads();   // the ONLY barrier

    f32x16 acc00 = {}, acc01 = {}, acc10 = {}, acc11 = {};
    const s16x8* wB = (const s16x8*)wbf;
    const int bbase = wn * 64 + l31 + hi * 128;

#define LOADB(dst, tap) do {                                                   \
    _Pragma("unroll") for (int cc = 0; cc < 4; ++cc) {                         \
        dst[2*cc]   = wB[(tap) * 1024 + cc * 256 + bbase];                     \
        dst[2*cc+1] = wB[(tap) * 1024 + cc * 256 + bbase + 32];                \
    } } while (0)

#define COMP(bb, tap) do {                                                     \
    const int i_ = (tap) / 3, j_ = (tap) % 3;                                  \
    const unsigned aCol = (unsigned)(l31 + j_) * 16;                           \
    _Pragma("unroll") for (int cc = 0; cc < 4; ++cc) {                         \
        const unsigned rr = (unsigned)((wm + i_) * 8 + cc * 2 + hi);           \
        const unsigned aO0 = rr * XROW + aCol;                                 \
        s16x8 a0 = *(const s16x8*)(lds_x + aO0);                               \
        s16x8 a1 = *(const s16x8*)(lds_x + aO0 + 32 * 16);                     \
        acc00 = __builtin_amdgcn_mfma_f32_32x32x16_bf16(a0, bb[2*cc],   acc00, 0, 0, 0); \
        acc01 = __builtin_amdgcn_mfma_f32_32x32x16_bf16(a0, bb[2*cc+1], acc01, 0, 0, 0); \
        acc10 = __builtin_amdgcn_mfma_f32_32x32x16_bf16(a1, bb[2*cc],   acc10, 0, 0, 0); \
        acc11 = __builtin_amdgcn_mfma_f32_32x32x16_bf16(a1, bb[2*cc+1], acc11, 0, 0, 0); \
    } } while (0)

    s16x8 bA[8], bB[8];
    LOADB(bA, 0);
    #pragma unroll
    for (int tt = 0; tt < 4; ++tt) {
        LOADB(bB, 2 * tt + 1);
        COMP(bA, 2 * tt);
        LOADB(bA, 2 * tt + 2);
        COMP(bB, 2 * tt + 1);
    }
    COMP(bA, 8);

    // epilogue: D row=(reg&3)+8*(reg>>2)+4*hi (w), col=l31 (co)
    const int h = h0 + wm;
    #pragma unroll
    for (int fn = 0; fn < 2; ++fn) {
        const int co = wn * 64 + fn * 32 + l31;
        const float bv = bias[co];
        float* op = out + (((size_t)n * COUT + co) * CH_ + h) * CW_ + 4 * hi;
        #pragma unroll
        for (int fm = 0; fm < 2; ++fm) {
            const f32x16 a = fn == 0 ? (fm == 0 ? acc00 : acc10)
                                     : (fm == 0 ? acc01 : acc11);
            #pragma unroll
            for (int q = 0; q < 4; ++q) {
                float4 v = make_float4(a[4*q+0] + bv, a[4*q+1] + bv,
                                       a[4*q+2] + bv, a[4*q+3] + bv);
                *(float4*)(op + fm * 32 + 8 * q) = v;
            }
        }
    }
#undef LOADB
#undef COMP
}

// ---- fallback (ws too small)
__global__ __launch_bounds__(256) void conv_direct_f32(
    const float* __restrict__ x, const float* __restrict__ wgt,
    const float* __restrict__ bias, float* __restrict__ out)
{
    const int w = threadIdx.x, ty = threadIdx.y;
    const int cog = blockIdx.x, h = blockIdx.y, n = blockIdx.z;
    const int co0 = cog * 32 + ty * 8;
    float acc[8];
    #pragma unroll
    for (int k = 0; k < 8; ++k) acc[k] = bias[co0 + k];
    const float* xn = x + (size_t)n * CIN * CH_ * CW_;
    for (int c = 0; c < CIN; ++c) {
        const float* xc = xn + (size_t)c * CH_ * CW_;
        #pragma unroll
        for (int i = 0; i < 3; ++i) {
            const int hh = h - 1 + i;
            if (hh < 0 || hh >= CH_) continue;
            const float* xr = xc + hh * CW_;
            #pragma unroll
            for (int j = 0; j < 3; ++j) {
                const int ww = w - 1 + j;
                const float v = (ww >= 0 && ww < CW_) ? xr[ww] : 0.0f;
                const float* wp = wgt + (size_t)((c * 9 + i * 3 + j) * COUT) + co0;
                const float4 w0 = *reinterpret_cast<const float4*>(wp);
                const float4 w1 = *reinterpret_cast<const float4*>(wp + 4);
                acc[0] += v * w0.x; acc[1] += v * w0.y; acc[2] += v * w0.z; acc[3] += v * w0.w;
                acc[4] += v * w1.x; acc[5] += v * w1.y; acc[6] += v * w1.z; acc[7] += v * w1.w;
            }
        }
    }
    float* op = out + (((size_t)n * COUT + co0) * CH_ + h) * CW_ + w;
    #pragma unroll
    for (int k = 0; k < 8; ++k) op[(size_t)k * CH_ * CW_] = acc[k];
}

extern "C" void kernel_launch(void* const* d_in, const int* in_sizes, int n_in,
                              void* d_out, int out_size, void* d_ws, size_t ws_size,
                              hipStream_t stream) {
    const float* x    = (const float*)d_in[0];
    const float* wgt  = (const float*)d_in[1];
    const float* bias = (const float*)d_in[2];
    float* out        = (float*)d_out;

    if (ws_size >= (size_t)(9 * 8 * 128 * 8) * sizeof(unsigned short)) {
        wconv_prep<<<288, 256, 0, stream>>>(wgt, (unsigned short*)d_ws);
        conv_mfma<<<1024, 256, 0, stream>>>(x, bias, (const unsigned short*)d_ws, out);
    } else {
        conv_direct_f32<<<dim3(4, 64, 32), dim3(64, 4, 1), 0, stream>>>(x, wgt, bias, out);
    }
}

// Round 5
// 113.980 us; speedup vs baseline: 1.0023x; 1.0023x over previous
//
#include <hip/hip_runtime.h>
#include <cstdint>
#include <cstddef>

#define CIN   64
#define CH_   64
#define CW_   64
#define COUT  128

typedef short  s16x8  __attribute__((ext_vector_type(8)));
typedef float  f32x16 __attribute__((ext_vector_type(16)));

__device__ __forceinline__ unsigned short f32_to_bf16(float f) {
    unsigned int u = __builtin_bit_cast(unsigned int, f);
    u = u + 0x7FFFu + ((u >> 16) & 1u);          // RNE
    return (unsigned short)(u >> 16);
}

// ---- pre-kernel: f32 (C*9, 128) -> bf16 [tap][chunk][co][8ch], coalesced reads
__global__ __launch_bounds__(256) void wconv_prep(const float* __restrict__ wgt,
                                                  unsigned short* __restrict__ wdst) {
    int tid = blockIdx.x * 256 + threadIdx.x;
    if (tid >= 576 * 128) return;
    int row = tid >> 7;            // c*9 + tap
    int co  = tid & 127;
    int c   = row / 9;
    int tap = row - c * 9;
    float f = wgt[tid];            // coalesced
    wdst[((tap * 8 + (c >> 3)) * 128 + co) * 8 + (c & 7)] = f32_to_bf16(f);
}

// ---- main: implicit GEMM, 256(spatial=4h x 64w) x 128(co) per block, 4 waves
// Each wave: 2h x 64w x 64co via 8 accs. Operand-swapped MFMA (A=w, B=x) -> dense stores.
// LDS x: [r:6][ck:8][t:67*16B] conflict-free both sides.
#define XROW 1072   // 67 * 16 bytes
#define MFMA_SW(d, wf, xf) d = __builtin_amdgcn_mfma_f32_32x32x16_bf16((wf), (xf), (d), 0, 0, 0)

__global__ __launch_bounds__(256, 2) void conv_mfma(
    const float* __restrict__ x,            // (N,64,64,64) f32
    const float* __restrict__ bias,         // (128)
    const unsigned short* __restrict__ wbf, // bf16 [tap][chunk][co][8], in ws (L2-resident)
    float* __restrict__ out)                // (N,128,64,64) f32
{
    __shared__ __align__(16) unsigned char lds_x[48 * XROW];   // 51456 B

    const int tid  = threadIdx.x;
    const int lane = tid & 63;
    const int wid  = tid >> 6;
    const int hi   = lane >> 5;
    const int l31  = lane & 31;
    const int wm   = wid >> 1;        // h-pair within tile (0/1)
    const int wn   = wid & 1;         // co half

    // XCD-bijective swizzle: 512 blocks = 8 * 64
    const int bid = blockIdx.x;
    const int swz = (bid & 7) * 64 + (bid >> 3);
    const int n   = swz >> 4;         // 0..31
    const int hb  = swz & 15;         // 0..15
    const int h0  = hb * 4;

    const s16x8* wB = (const s16x8*)wbf;
    const int bbase = wn * 64 + l31 + hi * 128;

#define LOADB(dst, tap) do {                                                   \
    _Pragma("unroll") for (int cc = 0; cc < 4; ++cc) {                         \
        dst[2*cc]   = wB[(tap) * 1024 + cc * 256 + bbase];                     \
        dst[2*cc+1] = wB[(tap) * 1024 + cc * 256 + bbase + 32];                \
    } } while (0)

    s16x8 bA[8], bB[8];
    LOADB(bA, 0);          // in flight during x staging
    LOADB(bB, 1);

    // ---- stage x tile: rows h0-1..h0+4 (r=0..5), cols -1..64 (t=0..65), 64 ch bf16
    const float* xn = x + (size_t)n * CIN * CH_ * CW_;
    #pragma unroll
    for (int it = 0; it < 3; ++it) {
        const int idx = tid + it * 256;         // 768 items
        const int g  = idx & 15;                // w-group of 4
        const int ck = (idx >> 4) & 7;          // channel chunk
        const int r  = idx >> 7;                // tile row 0..5
        const int grow = h0 - 1 + r;
        s16x8 pk[4] = {};
        if (grow >= 0 && grow < CH_) {
            #pragma unroll
            for (int e = 0; e < 8; ++e) {
                const float4 v = *(const float4*)(xn + ((size_t)(ck * 8 + e) * CH_ + grow) * CW_ + 4 * g);
                pk[0][e] = (short)f32_to_bf16(v.x);
                pk[1][e] = (short)f32_to_bf16(v.y);
                pk[2][e] = (short)f32_to_bf16(v.z);
                pk[3][e] = (short)f32_to_bf16(v.w);
            }
        }
        unsigned char* rowp = lds_x + (r * 8 + ck) * XROW;
        #pragma unroll
        for (int q = 0; q < 4; ++q)
            *(s16x8*)(rowp + (4 * g + 1 + q) * 16) = pk[q];
    }
    if (tid < 96) {   // zero pads t=0 and t=65 for all 48 (r,ck)
        const int t  = (tid & 1) ? 65 : 0;
        const int ck = (tid >> 1) & 7;
        const int r  = tid >> 4;
        s16x8 z = {};
        *(s16x8*)(lds_x + (r * 8 + ck) * XROW + t * 16) = z;
    }
    __syncthreads();   // the ONLY barrier

    // ---- accumulators accRST: R=h-row(0/1), S=w-half(0/1), T=co-half(0/1); C-init = bias
    f32x16 acc000, acc001, acc010, acc011, acc100, acc101, acc110, acc111;
    #pragma unroll
    for (int r = 0; r < 16; ++r) {
        const int cq = 4 * hi + (r & 3) + 8 * (r >> 2);
        const float bv0 = bias[wn * 64 + cq];
        const float bv1 = bias[wn * 64 + 32 + cq];
        acc000[r] = bv0; acc010[r] = bv0; acc100[r] = bv0; acc110[r] = bv0;
        acc001[r] = bv1; acc011[r] = bv1; acc101[r] = bv1; acc111[r] = bv1;
    }

#define COMP(bb, tap) do {                                                     \
    const int i_ = (tap) / 3, j_ = (tap) % 3;                                  \
    const unsigned aCol = (unsigned)(l31 + j_) * 16;                           \
    _Pragma("unroll") for (int cc = 0; cc < 4; ++cc) {                         \
        const unsigned ch = (unsigned)(cc * 2 + hi);                           \
        const unsigned aO = ((unsigned)(2 * wm + i_) * 8 + ch) * XROW + aCol;  \
        s16x8 a00 = *(const s16x8*)(lds_x + aO);                               \
        s16x8 a01 = *(const s16x8*)(lds_x + aO + 512);                         \
        s16x8 a10 = *(const s16x8*)(lds_x + aO + 8 * XROW);                    \
        s16x8 a11 = *(const s16x8*)(lds_x + aO + 8 * XROW + 512);              \
        MFMA_SW(acc000, bb[2*cc],   a00);                                      \
        MFMA_SW(acc001, bb[2*cc+1], a00);                                      \
        MFMA_SW(acc010, bb[2*cc],   a01);                                      \
        MFMA_SW(acc011, bb[2*cc+1], a01);                                      \
        MFMA_SW(acc100, bb[2*cc],   a10);                                      \
        MFMA_SW(acc101, bb[2*cc+1], a10);                                      \
        MFMA_SW(acc110, bb[2*cc],   a11);                                      \
        MFMA_SW(acc111, bb[2*cc+1], a11);                                      \
    } } while (0)

    COMP(bA, 0); LOADB(bA, 2);
    COMP(bB, 1); LOADB(bB, 3);
    COMP(bA, 2); LOADB(bA, 4);
    COMP(bB, 3); LOADB(bB, 5);
    COMP(bA, 4); LOADB(bA, 6);
    COMP(bB, 5); LOADB(bB, 7);
    COMP(bA, 6); LOADB(bA, 8);
    COMP(bB, 7);
    COMP(bA, 8);

    // ---- epilogue: D^T -> col(l31)=w, row(reg,hi)=co. Dense 128B runs per store.
    const int hB = h0 + 2 * wm;
    float* outn = out + (size_t)n * COUT * (CH_ * CW_);
    #pragma unroll
    for (int r = 0; r < 16; ++r) {
        const int cq = 4 * hi + (r & 3) + 8 * (r >> 2);
        float* p0 = outn + (size_t)(wn * 64 + cq) * (CH_ * CW_) + hB * CW_ + l31;
        float* p1 = outn + (size_t)(wn * 64 + 32 + cq) * (CH_ * CW_) + hB * CW_ + l31;
        p0[0]  = acc000[r];  p0[32]      = acc010[r];
        p0[64] = acc100[r];  p0[64 + 32] = acc110[r];
        p1[0]  = acc001[r];  p1[32]      = acc011[r];
        p1[64] = acc101[r];  p1[64 + 32] = acc111[r];
    }
#undef LOADB
#undef COMP
}

// ---- fallback (ws too small)
__global__ __launch_bounds__(256) void conv_direct_f32(
    const float* __restrict__ x, const float* __restrict__ wgt,
    const float* __restrict__ bias, float* __restrict__ out)
{
    const int w = threadIdx.x, ty = threadIdx.y;
    const int cog = blockIdx.x, h = blockIdx.y, n = blockIdx.z;
    const int co0 = cog * 32 + ty * 8;
    float acc[8];
    #pragma unroll
    for (int k = 0; k < 8; ++k) acc[k] = bias[co0 + k];
    const float* xn = x + (size_t)n * CIN * CH_ * CW_;
    for (int c = 0; c < CIN; ++c) {
        const float* xc = xn + (size_t)c * CH_ * CW_;
        #pragma unroll
        for (int i = 0; i < 3; ++i) {
            const int hh = h - 1 + i;
            if (hh < 0 || hh >= CH_) continue;
            const float* xr = xc + hh * CW_;
            #pragma unroll
            for (int j = 0; j < 3; ++j) {
                const int ww = w - 1 + j;
                const float v = (ww >= 0 && ww < CW_) ? xr[ww] : 0.0f;
                const float* wp = wgt + (size_t)((c * 9 + i * 3 + j) * COUT) + co0;
                const float4 w0 = *reinterpret_cast<const float4*>(wp);
                const float4 w1 = *reinterpret_cast<const float4*>(wp + 4);
                acc[0] += v * w0.x; acc[1] += v * w0.y; acc[2] += v * w0.z; acc[3] += v * w0.w;
                acc[4] += v * w1.x; acc[5] += v * w1.y; acc[6] += v * w1.z; acc[7] += v * w1.w;
            }
        }
    }
    float* op = out + (((size_t)n * COUT + co0) * CH_ + h) * CW_ + w;
    #pragma unroll
    for (int k = 0; k < 8; ++k) op[(size_t)k * CH_ * CW_] = acc[k];
}

extern "C" void kernel_launch(void* const* d_in, const int* in_sizes, int n_in,
                              void* d_out, int out_size, void* d_ws, size_t ws_size,
                              hipStream_t stream) {
    const float* x    = (const float*)d_in[0];
    const float* wgt  = (const float*)d_in[1];
    const float* bias = (const float*)d_in[2];
    float* out        = (float*)d_out;

    if (ws_size >= (size_t)(9 * 8 * 128 * 8) * sizeof(unsigned short)) {
        wconv_prep<<<288, 256, 0, stream>>>(wgt, (unsigned short*)d_ws);
        conv_mfma<<<512, 256, 0, stream>>>(x, bias, (const unsigned short*)d_ws, out);
    } else {
        conv_direct_f32<<<dim3(4, 64, 32), dim3(64, 4, 1), 0, stream>>>(x, wgt, bias, out);
    }
}